// Round 15
// baseline (45.898 us; speedup 1.0000x reference)
//
#include <hip/hip_runtime.h>
#include <hip/hip_bf16.h>

#define CC 256
#define CMM 32
#define KW 7
#define KK 49
#define PADW 3
#define HH 56
#define WW 56
#define HP 62
#define LP 3844   // 62*62
#define LL 3136   // 56*56
#define BB 2
#define MM 8
#define MIDW 16

typedef __attribute__((ext_vector_type(8))) short bf16x8;
typedef __attribute__((ext_vector_type(4))) float f32x4;
typedef __attribute__((ext_vector_type(8))) unsigned short us8_t;
typedef __attribute__((ext_vector_type(4))) unsigned short us4_t;

__device__ inline short bfr(float f) {   // f32 -> bf16 bits, RNE
  unsigned int u = __builtin_bit_cast(unsigned int, f);
  u += 0x7fffu + ((u >> 16) & 1u);
  return (short)(u >> 16);
}
__device__ inline float bf2f(short h) {
  return __builtin_bit_cast(float, ((unsigned int)(unsigned short)h) << 16);
}

// ---------------- k/q 1x1 conv as bf16 MFMA GEMM (R14, unchanged) ----------
__global__ void __launch_bounds__(256) kq_kernel(
    const float* __restrict__ x,
    const float* __restrict__ k_w, const float* __restrict__ k_b,
    const float* __restrict__ q_w, const float* __restrict__ q_b,
    float* __restrict__ km, float* __restrict__ qm) {
  __shared__ unsigned short bsT[2][64][40];
  int t = threadIdx.x;
  int lane = t & 63;
  int w = t >> 6;
  int px0 = blockIdx.x * 64;
  int b = blockIdx.z;
  int l15 = lane & 15;
  int hi = lane >> 4;

  int oc_a = w * 16 + l15;
  const float* wrow = ((oc_a < CMM) ? (k_w + (size_t)oc_a * CC)
                                    : (q_w + (size_t)(oc_a - CMM) * CC)) + hi * 8;
  bf16x8 ah[8], al[8];
  #pragma unroll
  for (int s = 0; s < 8; ++s) {
    f32x4 w0 = *(const f32x4*)(wrow + s * 32);
    f32x4 w1 = *(const f32x4*)(wrow + s * 32 + 4);
    bf16x8 h, l;
    #pragma unroll
    for (int j = 0; j < 4; ++j) {
      short hb0 = bfr(w0[j]); h[j] = hb0;     l[j] = bfr(w0[j] - bf2f(hb0));
      short hb1 = bfr(w1[j]); h[j + 4] = hb1; l[j + 4] = bfr(w1[j] - bf2f(hb1));
    }
    ah[s] = h; al[s] = l;
  }

  int spx = t & 63;
  int skb = (t >> 6) * 8;
  const float* xg = x + (size_t)b * CC * LL + px0 + spx;

  {
    float fv[8];
    #pragma unroll
    for (int j = 0; j < 8; ++j) fv[j] = xg[(size_t)(skb + j) * LL];
    us8_t hv;
    #pragma unroll
    for (int j = 0; j < 8; ++j) hv[j] = (unsigned short)bfr(fv[j]);
    *(us8_t*)&bsT[0][spx][skb] = hv;
  }

  f32x4 acc[4];
  #pragma unroll
  for (int q = 0; q < 4; ++q) acc[q] = {0.f, 0.f, 0.f, 0.f};

  for (int s = 0; s < 8; ++s) {
    __syncthreads();
    float fv[8];
    if (s < 7) {
      #pragma unroll
      for (int j = 0; j < 8; ++j)
        fv[j] = xg[(size_t)((s + 1) * 32 + skb + j) * LL];
    }
    int cur = s & 1;
    #pragma unroll
    for (int q = 0; q < 4; ++q) {
      bf16x8 bv = *(const bf16x8*)&bsT[cur][q * 16 + l15][hi * 8];
      acc[q] = __builtin_amdgcn_mfma_f32_16x16x32_bf16(ah[s], bv, acc[q], 0, 0, 0);
      acc[q] = __builtin_amdgcn_mfma_f32_16x16x32_bf16(al[s], bv, acc[q], 0, 0, 0);
    }
    if (s < 7) {
      us8_t hv;
      #pragma unroll
      for (int j = 0; j < 8; ++j) hv[j] = (unsigned short)bfr(fv[j]);
      *(us8_t*)&bsT[cur ^ 1][spx][skb] = hv;
    }
  }

  #pragma unroll
  for (int q = 0; q < 4; ++q) {
    #pragma unroll
    for (int rr = 0; rr < 4; ++rr) {
      int oc = w * 16 + hi * 4 + rr;
      int px = px0 + q * 16 + l15;
      if (oc < CMM)
        km[((size_t)b * CMM + oc) * LL + px] = acc[q][rr] + k_b[oc];
      else
        qm[((size_t)b * CMM + (oc - CMM)) * LL + px] = acc[q][rr] + q_b[oc - CMM];
    }
  }
}

// ---------------- fused QK * softmax * PV: 2-col threads, float2 LDS --------
// Block 256 thr = 4 waves (wave = band row). Lane = (cg 0..27, mh 0..1);
// thread: 2 cols x 4 m. Window reads = 4x aligned float2 (2-way max = free).
// Softmax duplicated only 2x (vs 4x in R13's failed variant).
__global__ void __launch_bounds__(256) attn_kernel(
    const float* __restrict__ x, const float* __restrict__ km,
    const float* __restrict__ qm,
    const float* __restrict__ gp_w1, const float* __restrict__ gp_b1,
    const float* __restrict__ gp_w2, const float* __restrict__ gp_b2,
    const float* __restrict__ k_b,
    unsigned short* __restrict__ pre) {
  __shared__ float xs[MM][10][64];
  __shared__ float ks[10][64];
  __shared__ float gs[KK];
  int t = threadIdx.x;
  int cm = blockIdx.y;
  int b = blockIdx.z;
  int y0 = blockIdx.x * 4;

  if (t < KK) {
    int i = t / KW, j = t % KW;
    float xpos = (float)(j - PADW), ypos = (float)(PADW - i);
    float a = gp_b2[cm];
    #pragma unroll
    for (int m = 0; m < MIDW; ++m) {
      float h = fmaxf(gp_w1[2 * m] * xpos + gp_w1[2 * m + 1] * ypos + gp_b1[m], 0.f);
      a = fmaf(gp_w2[cm * MIDW + m], h, a);
    }
    gs[t] = a;
  }
  float kb_cm = k_b[cm];
  const float* kmb = km + ((size_t)b * CMM + cm) * LL;
  for (int e = t; e < 640; e += 256) {
    int ri = e >> 6, cl = e & 63;
    int rp = y0 + ri;
    bool inner = (rp >= PADW && rp < PADW + HH && cl >= PADW && cl < PADW + WW);
    ks[ri][cl] = inner ? kmb[(rp - PADW) * WW + (cl - PADW)] : kb_cm;
  }
  const float* xg = x + (size_t)b * CC * LL;
  for (int e = t; e < 640; e += 256) {
    int ri = e >> 6, cl = e & 63;
    int ir = y0 - PADW + ri;
    int ic = cl - PADW;
    bool ok = (ir >= 0 && ir < HH && ic >= 0 && ic < WW);
    int off = ok ? (ir * WW + ic) : 0;
    #pragma unroll
    for (int m = 0; m < MM; ++m)
      xs[m][ri][cl] = ok ? xg[(size_t)(m * CMM + cm) * LL + off] : 0.f;
  }
  __syncthreads();

  int w = t >> 6, lane = t & 63;
  int cg = lane & 31;                  // 0..27 active
  int mh = lane >> 5;                  // m-half: 0 -> m0..3, 1 -> m4..7
  int y = y0 + w;
  bool act = (cg < 28);
  int c0 = act ? cg * 2 : 0;
  float2 qc2 = *(const float2*)(qm + ((size_t)b * CMM + cm) * LL + y * WW + c0);

  float acc[4][2] = {{0.f,0.f},{0.f,0.f},{0.f,0.f},{0.f,0.f}};
  #pragma unroll
  for (int i = 0; i < KW; ++i) {
    int row = w + i;                   // 0..9
    float kv[8];
    *(float2*)&kv[0] = *(const float2*)&ks[row][c0];
    *(float2*)&kv[2] = *(const float2*)&ks[row][c0 + 2];
    *(float2*)&kv[4] = *(const float2*)&ks[row][c0 + 4];
    *(float2*)&kv[6] = *(const float2*)&ks[row][c0 + 6];
    float e0[KW], e1[KW];
    #pragma unroll
    for (int j = 0; j < KW; ++j) {
      float g = gs[i * KW + j];
      e0[j] = fmaf(kv[j], qc2.x, g);
      e1[j] = fmaf(kv[j + 1], qc2.y, g);
    }
    float mx0 = fmaxf(fmaxf(fmaxf(e0[0], e0[1]), fmaxf(e0[2], e0[3])),
                      fmaxf(fmaxf(e0[4], e0[5]), e0[6]));
    float mx1 = fmaxf(fmaxf(fmaxf(e1[0], e1[1]), fmaxf(e1[2], e1[3])),
                      fmaxf(fmaxf(e1[4], e1[5]), e1[6]));
    float sum0 = 0.f, sum1 = 0.f;
    #pragma unroll
    for (int j = 0; j < KW; ++j) {
      e0[j] = __expf(e0[j] - mx0); sum0 += e0[j];
      e1[j] = __expf(e1[j] - mx1); sum1 += e1[j];
    }
    float inv0 = __builtin_amdgcn_rcpf(sum0);
    float inv1 = __builtin_amdgcn_rcpf(sum1);
    #pragma unroll
    for (int mm = 0; mm < 4; ++mm) {
      const float* xr = &xs[mh * 4 + mm][row][0];
      float xv[8];
      *(float2*)&xv[0] = *(const float2*)(xr + c0);
      *(float2*)&xv[2] = *(const float2*)(xr + c0 + 2);
      *(float2*)&xv[4] = *(const float2*)(xr + c0 + 4);
      *(float2*)&xv[6] = *(const float2*)(xr + c0 + 6);
      float d0 = e0[0] * xv[0];
      float d1 = e1[0] * xv[1];
      #pragma unroll
      for (int j = 1; j < KW; ++j) {
        d0 = fmaf(e0[j], xv[j], d0);
        d1 = fmaf(e1[j], xv[j + 1], d1);
      }
      acc[mm][0] = fmaf(d0, inv0, acc[mm][0]);
      acc[mm][1] = fmaf(d1, inv1, acc[mm][1]);
    }
  }
  if (act) {
    #pragma unroll
    for (int mm = 0; mm < 4; ++mm) {
      int m = mh * 4 + mm;
      unsigned int lo = (unsigned short)bfr(acc[mm][0]);
      unsigned int hi2 = (unsigned short)bfr(acc[mm][1]);
      *(unsigned int*)(pre + ((size_t)b * CC + m * CMM + cm) * LL + y * WW + c0) =
          lo | (hi2 << 16);
    }
  }
}

// ---------------- final 1x1 conv: bf16 MFMA, transposed LDS B (R14) ---------
__global__ void __launch_bounds__(256) fconv_kernel(
    const unsigned short* __restrict__ preb,
    const float* __restrict__ f_w, const float* __restrict__ f_b,
    float* __restrict__ out) {
  __shared__ unsigned short bsT[2][64][40];
  int t = threadIdx.x;
  int lane = t & 63;
  int w = t >> 6;
  int px0 = blockIdx.x * 64;
  int oc0 = blockIdx.y * 64;
  int b = blockIdx.z;
  int l15 = lane & 15;
  int hi = lane >> 4;

  bf16x8 af[8];
  const float* wrow = f_w + (size_t)(oc0 + w * 16 + l15) * CC + hi * 8;
  #pragma unroll
  for (int s = 0; s < 8; ++s) {
    f32x4 w0 = *(const f32x4*)(wrow + s * 32);
    f32x4 w1 = *(const f32x4*)(wrow + s * 32 + 4);
    bf16x8 a;
    #pragma unroll
    for (int j = 0; j < 4; ++j) { a[j] = bfr(w0[j]); a[j + 4] = bfr(w1[j]); }
    af[s] = a;
  }

  int spx = t & 63;
  int skb = (t >> 6) * 8;
  const unsigned short* pg = preb + (size_t)b * CC * LL + px0 + spx;

  {
    us8_t hv;
    #pragma unroll
    for (int j = 0; j < 8; ++j) hv[j] = pg[(size_t)(skb + j) * LL];
    *(us8_t*)&bsT[0][spx][skb] = hv;
  }

  f32x4 acc[4];
  #pragma unroll
  for (int q = 0; q < 4; ++q) acc[q] = {0.f, 0.f, 0.f, 0.f};

  for (int s = 0; s < 8; ++s) {
    __syncthreads();
    unsigned short vn[8];
    if (s < 7) {
      #pragma unroll
      for (int j = 0; j < 8; ++j)
        vn[j] = pg[(size_t)((s + 1) * 32 + skb + j) * LL];
    }
    int cur = s & 1;
    #pragma unroll
    for (int q = 0; q < 4; ++q) {
      bf16x8 bv = *(const bf16x8*)&bsT[cur][q * 16 + l15][hi * 8];
      acc[q] = __builtin_amdgcn_mfma_f32_16x16x32_bf16(af[s], bv, acc[q], 0, 0, 0);
    }
    if (s < 7) {
      us8_t hv;
      #pragma unroll
      for (int j = 0; j < 8; ++j) hv[j] = vn[j];
      *(us8_t*)&bsT[cur ^ 1][spx][skb] = hv;
    }
  }

  #pragma unroll
  for (int q = 0; q < 4; ++q) {
    #pragma unroll
    for (int rr = 0; rr < 4; ++rr) {
      int oc = oc0 + w * 16 + hi * 4 + rr;
      out[((size_t)b * CC + oc) * LL + px0 + q * 16 + l15] = acc[q][rr] + f_b[oc];
    }
  }
}

extern "C" void kernel_launch(void* const* d_in, const int* in_sizes, int n_in,
                              void* d_out, int out_size, void* d_ws, size_t ws_size,
                              hipStream_t stream) {
  const float* x     = (const float*)d_in[0];
  const float* k_w   = (const float*)d_in[1];
  const float* k_b   = (const float*)d_in[2];
  const float* q_w   = (const float*)d_in[3];
  const float* q_b   = (const float*)d_in[4];
  const float* gp_w1 = (const float*)d_in[5];
  const float* gp_b1 = (const float*)d_in[6];
  const float* gp_w2 = (const float*)d_in[7];
  const float* gp_b2 = (const float*)d_in[8];
  const float* f_w   = (const float*)d_in[9];
  const float* f_b   = (const float*)d_in[10];
  float* out = (float*)d_out;

  float* ws  = (float*)d_ws;
  float* km  = ws;                                   // 2*32*3136 f32 (inner)
  float* qm  = km + (size_t)BB * CMM * LL;
  unsigned short* pre = (unsigned short*)(qm + (size_t)BB * CMM * LL); // bf16

  hipLaunchKernelGGL(kq_kernel, dim3(LL / 64, 1, BB), dim3(256), 0, stream,
                     x, k_w, k_b, q_w, q_b, km, qm);
  hipLaunchKernelGGL(attn_kernel, dim3(HH / 4, CMM, BB), dim3(256), 0, stream,
                     x, km, qm, gp_w1, gp_b1, gp_w2, gp_b2, k_b, pre);
  hipLaunchKernelGGL(fconv_kernel, dim3(LL / 64, CC / 64, BB), dim3(256), 0, stream,
                     pre, f_w, f_b, out);
}